// Round 16
// baseline (87.427 us; speedup 1.0000x reference)
//
#include <hip/hip_runtime.h>
#include <hip/hip_bf16.h>
#include <cmath>

#define B_SZ 4096
#define N_SZ 8192
#define D_SZ 256
#define EPS 1e-8f
// zn is stored as fp8 e4m3 scaled by 16 -> acc = 256*cos.
// exp(sim-2) with sim = 2*cos = acc/128:  exp2( acc*log2e/128 - 2*log2e )
#define EXPC 0.01127105500694503f      // log2(e)/128
#define EXPB -2.8853900817779268f      // -2*log2(e)

typedef __attribute__((ext_vector_type(4))) float f32x4;
typedef __attribute__((ext_vector_type(4))) int   i32x4;
typedef __attribute__((ext_vector_type(8))) int   i32x8;

__device__ __forceinline__ void dma16(const void* g, void* l) {
    __builtin_amdgcn_global_load_lds(
        (const __attribute__((address_space(1))) unsigned int*)g,
        (__attribute__((address_space(3))) unsigned int*)l, 16, 0, 0);
}

// fp8 k-segment-transposed panel layout (1 byte/elem):
//   byte(row,k) = (row>>6)*16384 + (k>>4)*1024 + (row&63)*16 + (k&15)
// subpanel = 64 rows x 256 k = 16 KB. One K=128 MFMA operand (32 fp8) = two
// 16-B loads 1024 B apart.

// ---- Kernel 1: norms + pos (fp32 exact) + fp8 ZN + zero the reduce ctrl. ----
__global__ __launch_bounds__(256) void prep_kernel(const float* __restrict__ zi,
                                                   const float* __restrict__ zj,
                                                   char* __restrict__ znb,
                                                   float* __restrict__ pos,
                                                   float* __restrict__ accf,
                                                   unsigned* __restrict__ counter) {
    if (blockIdx.x == 0 && threadIdx.x == 0) { *accf = 0.0f; *counter = 0u; }
    const int wave = threadIdx.x >> 6, lane = threadIdx.x & 63;
    const int i = blockIdx.x * 4 + wave;               // 0..B-1
    float4 a = reinterpret_cast<const float4*>(zi + (size_t)i * D_SZ)[lane];
    float4 b = reinterpret_cast<const float4*>(zj + (size_t)i * D_SZ)[lane];
    float ssa = a.x * a.x + a.y * a.y + a.z * a.z + a.w * a.w;
    float ssb = b.x * b.x + b.y * b.y + b.z * b.z + b.w * b.w;
    float dab = a.x * b.x + a.y * b.y + a.z * b.z + a.w * b.w;
    #pragma unroll
    for (int off = 32; off; off >>= 1) {
        ssa += __shfl_xor(ssa, off, 64);
        ssb += __shfl_xor(ssb, off, 64);
        dab += __shfl_xor(dab, off, 64);
    }
    const float invna = 1.0f / fmaxf(sqrtf(ssa), EPS);
    const float invnb = 1.0f / fmaxf(sqrtf(ssb), EPS);
    if (lane == 0) {
        float p = dab * invna * invnb * 2.0f;
        pos[i] = p;
        pos[i + B_SZ] = p;
    }
    // lane covers k = 4*lane .. 4*lane+3; seg = lane>>2, in-seg byte = (lane&3)*4.
    const float sa = invna * 16.0f, sb = invnb * 16.0f;
    const int koff = (lane >> 2) * 1024 + (lane & 3) * 4;
    {
        int pk = __builtin_amdgcn_cvt_pk_fp8_f32(a.x * sa, a.y * sa, 0, false);
        pk     = __builtin_amdgcn_cvt_pk_fp8_f32(a.z * sa, a.w * sa, pk, true);
        *reinterpret_cast<int*>(znb + (size_t)(i >> 6) * 16384 + koff + (i & 63) * 16) = pk;
    }
    {
        const int r = i + B_SZ;
        int pk = __builtin_amdgcn_cvt_pk_fp8_f32(b.x * sb, b.y * sb, 0, false);
        pk     = __builtin_amdgcn_cvt_pk_fp8_f32(b.z * sb, b.w * sb, pk, true);
        *reinterpret_cast<int*>(znb + (size_t)(r >> 6) * 16384 + koff + (r & 63) * 16) = pk;
    }
}

// ---- Kernel 2: SYMMETRIC fp8 K=128 sim-GEMM + exp-sum, LDS-staged B ----
// r15 core, unchanged. 528 triangular blocks x 512 thr (8 waves, M_w=32).
__global__ __launch_bounds__(512, 4) void simlse_kernel(const char* __restrict__ znb,
                                                        float* __restrict__ partial) {
    __shared__ __attribute__((aligned(16))) char blds[65536];
    __shared__ float cs[8][256];

    const int t = threadIdx.x;
    const int wave = t >> 6, lane = t & 63;

    // Triangular decode: blockIdx.x in [0,528) -> (rt, chunk), rt <= chunk.
    int bid = blockIdx.x, rt = 0;
    #pragma unroll 1
    for (; rt < 32; ++rt) {
        int cnt = 32 - rt;
        if (bid < cnt) break;
        bid -= cnt;
    }
    const int chunk = rt + bid;
    const bool offdiag = (rt != chunk);

    const int rl = lane & 15;                    // A-row / B-col within fragment
    const int kg = lane >> 4;                    // 32-elem k-block index
    const int i0 = rt * 256 + wave * 32;         // wave's first row

    // Stage chunk's 64 KB B panel linearly: 512 thr x 8 x 16 B.
    {
        const char* gp = znb + (size_t)chunk * 65536 + t * 16;
        char* lp = blds + t * 16;
        #pragma unroll
        for (int c = 0; c < 8; ++c) dma16(gp + c * 8192, lp + c * 8192);
    }

    // A panel: 2 rowgroups x 2 k-chunks of 128 (loads overlap the DMA).
    const char* ap = znb + (size_t)(rt * 4 + (wave >> 1)) * 16384 +
                     (wave & 1) * 512 + rl * 16;
    i32x8 afrag[2][2];
    #pragma unroll
    for (int g = 0; g < 2; ++g)
        #pragma unroll
        for (int kc = 0; kc < 2; ++kc) {
            i32x4 lo = *reinterpret_cast<const i32x4*>(
                ap + (kc * 8 + kg * 2) * 1024 + g * 256);
            i32x4 hi = *reinterpret_cast<const i32x4*>(
                ap + (kc * 8 + kg * 2 + 1) * 1024 + g * 256);
            afrag[g][kc] = __builtin_shufflevector(lo, hi, 0, 1, 2, 3, 4, 5, 6, 7);
        }

    float s_acc[2][4];
    #pragma unroll
    for (int g = 0; g < 2; ++g)
        #pragma unroll
        for (int r = 0; r < 4; ++r) s_acc[g][r] = 0.0f;

    // B base in LDS; phase f (0..15): addr = bp0 + (f>>2)*16384 + (f&3)*256
    //   (+8192 for kc=1, +1024 for hi 16 B of the 32-elem k-block)
    const char* bp0 = blds + kg * 2048 + rl * 16;

    i32x8 bfA0, bfA1, bfB0, bfB1;                // double-buffered B fragments
    f32x4 accA[2], accB[2];

    #define LOADB(D0, D1, F)                                                      \
        {                                                                         \
            const char* bq = bp0 + ((F) >> 2) * 16384 + ((F) & 3) * 256;          \
            i32x4 l0 = *reinterpret_cast<const i32x4*>(bq);                       \
            i32x4 l1 = *reinterpret_cast<const i32x4*>(bq + 1024);                \
            i32x4 l2 = *reinterpret_cast<const i32x4*>(bq + 8192);                \
            i32x4 l3 = *reinterpret_cast<const i32x4*>(bq + 9216);                \
            D0 = __builtin_shufflevector(l0, l1, 0, 1, 2, 3, 4, 5, 6, 7);         \
            D1 = __builtin_shufflevector(l2, l3, 0, 1, 2, 3, 4, 5, 6, 7);         \
        }

    #define MFMA4(ACC, B0, B1)                                                    \
        {                                                                         \
            _Pragma("unroll")                                                     \
            for (int g = 0; g < 2; ++g) ACC[g] = (f32x4){0.f, 0.f, 0.f, 0.f};     \
            _Pragma("unroll")                                                     \
            for (int g = 0; g < 2; ++g)                                           \
                asm("v_mfma_f32_16x16x128_f8f6f4 %0, %1, %2, %0"                  \
                    : "+v"(ACC[g]) : "v"(afrag[g][0]), "v"(B0));                  \
            _Pragma("unroll")                                                     \
            for (int g = 0; g < 2; ++g)                                           \
                asm("v_mfma_f32_16x16x128_f8f6f4 %0, %1, %2, %0"                  \
                    : "+v"(ACC[g]) : "v"(afrag[g][1]), "v"(B1));                  \
        }

    #define EXPSUM(ACC, F)                                                        \
        {                                                                         \
            float cthr = 0.0f;                                                    \
            _Pragma("unroll")                                                     \
            for (int g = 0; g < 2; ++g)                                           \
                _Pragma("unroll")                                                 \
                for (int r = 0; r < 4; ++r) {                                     \
                    float e = __builtin_amdgcn_exp2f(fmaf(ACC[g][r], EXPC, EXPB)); \
                    s_acc[g][r] += e;                                             \
                    cthr += e;                                                    \
                }                                                                 \
            cthr += __shfl_xor(cthr, 16, 64);                                     \
            cthr += __shfl_xor(cthr, 32, 64);                                     \
            if (offdiag && lane < 16)                                             \
                cs[wave][((F) >> 2) * 64 + ((F) & 3) * 16 + rl] = cthr;           \
        }

    __syncthreads();                       // B panel landed (drains vmcnt)

    // Software pipeline: loads one phase ahead; EXPSUM one phase behind.
    LOADB(bfA0, bfA1, 0);
    LOADB(bfB0, bfB1, 1);
    MFMA4(accA, bfA0, bfA1);               // phase 0
    #pragma unroll 1
    for (int fo = 0; fo < 7; ++fo) {
        const int f1 = 2 * fo + 1, f2 = 2 * fo + 2;
        LOADB(bfA0, bfA1, f2);             // issue f2 loads (bfA free: consumed)
        MFMA4(accB, bfB0, bfB1);           // phase f1 (loads a phase old)
        asm volatile("s_nop 7");
        EXPSUM(accA, f1 - 1);
        LOADB(bfB0, bfB1, f2 + 1);         // issue f2+1 loads (<=15)
        MFMA4(accA, bfA0, bfA1);           // phase f2
        asm volatile("s_nop 7");
        EXPSUM(accB, f2 - 1);
    }
    MFMA4(accB, bfB0, bfB1);               // phase 15
    asm volatile("s_nop 7");
    EXPSUM(accA, 14);
    asm volatile("s_nop 7");
    EXPSUM(accB, 15);

    // Row-sums over the 16 col-lanes (rl); rows i0 + g*16 + kg*4 + r -> slot chunk.
    #pragma unroll
    for (int g = 0; g < 2; ++g)
        #pragma unroll
        for (int r = 0; r < 4; ++r) {
            float v = s_acc[g][r];
            #pragma unroll
            for (int off = 1; off < 16; off <<= 1) v += __shfl_xor(v, off, 64);
            if (rl == 0)
                partial[chunk * N_SZ + i0 + g * 16 + kg * 4 + r] = v;
        }

    // Col-sums: combine 8 waves, write 256 cols of the chunk-tile -> slot rt.
    if (offdiag) {
        __syncthreads();
        if (t < 256) {
            float v = 0.0f;
            #pragma unroll
            for (int w = 0; w < 8; ++w) v += cs[w][t];
            partial[rt * N_SZ + chunk * 256 + t] = v;
        }
    }
    #undef LOADB
    #undef MFMA4
    #undef EXPSUM
}

// ---- Kernel 3: per-row lse - pos; device-scope atomic final reduce ----
__global__ __launch_bounds__(256) void rowsum_kernel(const float* __restrict__ partial,
                                                     const float* __restrict__ pos,
                                                     float* __restrict__ accf,
                                                     unsigned* __restrict__ counter,
                                                     float* __restrict__ out) {
    const int row = blockIdx.x * 256 + threadIdx.x;
    float s = -1.0f;                       // remove diagonal exp(~0)=1
    #pragma unroll
    for (int c = 0; c < 32; ++c) s += partial[c * N_SZ + row];
    float acc = 2.0f + logf(s) - pos[row];
    #pragma unroll
    for (int off = 32; off; off >>= 1) acc += __shfl_xor(acc, off, 64);
    __shared__ float w[4];
    if ((threadIdx.x & 63) == 0) w[threadIdx.x >> 6] = acc;
    __syncthreads();
    if (threadIdx.x == 0) {
        atomicAdd(accf, w[0] + w[1] + w[2] + w[3]);
        __threadfence();
        unsigned old = atomicAdd(counter, 1u);
        if (old == 31u) {
            float tot = atomicAdd(accf, 0.0f);     // atomic read of final sum
            out[0] = tot / (float)N_SZ;
        }
    }
}

extern "C" void kernel_launch(void* const* d_in, const int* in_sizes, int n_in,
                              void* d_out, int out_size, void* d_ws, size_t ws_size,
                              hipStream_t stream) {
    const float* zi = (const float*)d_in[0];
    const float* zj = (const float*)d_in[1];

    char* ws = (char*)d_ws;
    char* znb       = ws;                                   // 2 MB fp8 k-seg layout
    float* pos      = (float*)(ws + 2097152);               // 32 KB
    float* partial  = (float*)(ws + 2097152 + 32768);       // 32*8192*4 = 1 MB
    float* accf     = (float*)(ws + 2097152 + 32768 + 1048576);
    unsigned* counter = (unsigned*)(ws + 2097152 + 32768 + 1048576 + 4);
    float* probe    = (float*)(ws + 3276800);               // 1 MB scratch (never read)
    float* out = (float*)d_out;

    prep_kernel<<<B_SZ / 4, 256, 0, stream>>>(zi, zj, znb, pos, accf, counter);
    // --- MEASUREMENT PROBE (r16): 3 identical simlse launches into scratch.
    // tau_simlse = (total_r16 - total_r15) / 3. Deterministic; probe never read.
    simlse_kernel<<<528, 512, 0, stream>>>(znb, probe);
    simlse_kernel<<<528, 512, 0, stream>>>(znb, probe);
    simlse_kernel<<<528, 512, 0, stream>>>(znb, probe);
    // --- real computation ---
    simlse_kernel<<<528, 512, 0, stream>>>(znb, partial);
    rowsum_kernel<<<32, 256, 0, stream>>>(partial, pos, accf, counter, out);
}

// Round 17
// 32.291 us; speedup vs baseline: 2.7075x; 2.7075x over previous
//
#include <hip/hip_runtime.h>
#include <hip/hip_bf16.h>
#include <cmath>

#define B_SZ 4096
#define N_SZ 8192
#define D_SZ 256
#define EPS 1e-8f
// zn is stored as fp8 e4m3 scaled by 16 -> acc = 256*cos.
// exp(sim-2) with sim = 2*cos = acc/128:  exp2( acc*log2e/128 - 2*log2e )
#define EXPC 0.01127105500694503f      // log2(e)/128
#define EXPB -2.8853900817779268f      // -2*log2(e)

typedef __attribute__((ext_vector_type(4))) float f32x4;
typedef __attribute__((ext_vector_type(4))) int   i32x4;
typedef __attribute__((ext_vector_type(8))) int   i32x8;

__device__ __forceinline__ void dma16(const void* g, void* l) {
    __builtin_amdgcn_global_load_lds(
        (const __attribute__((address_space(1))) unsigned int*)g,
        (__attribute__((address_space(3))) unsigned int*)l, 16, 0, 0);
}

// fp8 k-segment-transposed panel layout (1 byte/elem):
//   byte(row,k) = (row>>6)*16384 + (k>>4)*1024 + (row&63)*16 + (k&15)
// subpanel = 64 rows x 256 k = 16 KB. One K=128 MFMA operand (32 fp8) = two
// 16-B loads 1024 B apart.

// ---- Kernel 1: norms + pos (fp32 exact) + fp8 ZN + zero the reduce ctrl. ----
__global__ __launch_bounds__(256) void prep_kernel(const float* __restrict__ zi,
                                                   const float* __restrict__ zj,
                                                   char* __restrict__ znb,
                                                   float* __restrict__ pos,
                                                   float* __restrict__ accf,
                                                   unsigned* __restrict__ counter) {
    if (blockIdx.x == 0 && threadIdx.x == 0) { *accf = 0.0f; *counter = 0u; }
    const int wave = threadIdx.x >> 6, lane = threadIdx.x & 63;
    const int i = blockIdx.x * 4 + wave;               // 0..B-1
    float4 a = reinterpret_cast<const float4*>(zi + (size_t)i * D_SZ)[lane];
    float4 b = reinterpret_cast<const float4*>(zj + (size_t)i * D_SZ)[lane];
    float ssa = a.x * a.x + a.y * a.y + a.z * a.z + a.w * a.w;
    float ssb = b.x * b.x + b.y * b.y + b.z * b.z + b.w * b.w;
    float dab = a.x * b.x + a.y * b.y + a.z * b.z + a.w * b.w;
    #pragma unroll
    for (int off = 32; off; off >>= 1) {
        ssa += __shfl_xor(ssa, off, 64);
        ssb += __shfl_xor(ssb, off, 64);
        dab += __shfl_xor(dab, off, 64);
    }
    const float invna = 1.0f / fmaxf(sqrtf(ssa), EPS);
    const float invnb = 1.0f / fmaxf(sqrtf(ssb), EPS);
    if (lane == 0) {
        float p = dab * invna * invnb * 2.0f;
        pos[i] = p;
        pos[i + B_SZ] = p;
    }
    // lane covers k = 4*lane .. 4*lane+3; seg = lane>>2, in-seg byte = (lane&3)*4.
    const float sa = invna * 16.0f, sb = invnb * 16.0f;
    const int koff = (lane >> 2) * 1024 + (lane & 3) * 4;
    {
        int pk = __builtin_amdgcn_cvt_pk_fp8_f32(a.x * sa, a.y * sa, 0, false);
        pk     = __builtin_amdgcn_cvt_pk_fp8_f32(a.z * sa, a.w * sa, pk, true);
        *reinterpret_cast<int*>(znb + (size_t)(i >> 6) * 16384 + koff + (i & 63) * 16) = pk;
    }
    {
        const int r = i + B_SZ;
        int pk = __builtin_amdgcn_cvt_pk_fp8_f32(b.x * sb, b.y * sb, 0, false);
        pk     = __builtin_amdgcn_cvt_pk_fp8_f32(b.z * sb, b.w * sb, pk, true);
        *reinterpret_cast<int*>(znb + (size_t)(r >> 6) * 16384 + koff + (r & 63) * 16) = pk;
    }
}

// ---- Kernel 2: SYMMETRIC fp8 K=128 sim-GEMM + exp-sum, LDS-staged B ----
// r15 core, frozen. ONE change: XCD-aware paired-chunk tile assignment.
// XCD x = blockIdx%8 owns chunk-pairs (x, 31-x) and (x+8, 23-x): 33 tiles per
// pair, 66 per XCD (balanced), and each XCD's B working set is 4 chunks
// (256 KB) -> B panel staging becomes L2-local after first touch.
__global__ __launch_bounds__(512, 4) void simlse_kernel(const char* __restrict__ znb,
                                                        float* __restrict__ partial) {
    __shared__ __attribute__((aligned(16))) char blds[65536];
    __shared__ float cs[8][256];

    const int t = threadIdx.x;
    const int wave = t >> 6, lane = t & 63;

    // XCD-paired decode: d -> (rt, chunk), rt <= chunk.
    {
    }
    int rt, chunk;
    {
        const int x = blockIdx.x & 7;            // XCD (round-robin dispatch)
        int j = blockIdx.x >> 3;                 // 0..65 within XCD
        int p = x;                               // first pair: (x, 31-x)
        if (j >= 33) { j -= 33; p = x + 8; }     // second pair: (x+8, 23-x)
        if (j <= p) { rt = j; chunk = p; }       // chunk p has p+1 tiles
        else        { rt = j - (p + 1); chunk = 31 - p; }  // chunk 31-p: 32-p tiles
    }
    const bool offdiag = (rt != chunk);

    const int rl = lane & 15;                    // A-row / B-col within fragment
    const int kg = lane >> 4;                    // 32-elem k-block index
    const int i0 = rt * 256 + wave * 32;         // wave's first row

    // Stage chunk's 64 KB B panel linearly: 512 thr x 8 x 16 B.
    {
        const char* gp = znb + (size_t)chunk * 65536 + t * 16;
        char* lp = blds + t * 16;
        #pragma unroll
        for (int c = 0; c < 8; ++c) dma16(gp + c * 8192, lp + c * 8192);
    }

    // A panel: 2 rowgroups x 2 k-chunks of 128 (loads overlap the DMA).
    const char* ap = znb + (size_t)(rt * 4 + (wave >> 1)) * 16384 +
                     (wave & 1) * 512 + rl * 16;
    i32x8 afrag[2][2];
    #pragma unroll
    for (int g = 0; g < 2; ++g)
        #pragma unroll
        for (int kc = 0; kc < 2; ++kc) {
            i32x4 lo = *reinterpret_cast<const i32x4*>(
                ap + (kc * 8 + kg * 2) * 1024 + g * 256);
            i32x4 hi = *reinterpret_cast<const i32x4*>(
                ap + (kc * 8 + kg * 2 + 1) * 1024 + g * 256);
            afrag[g][kc] = __builtin_shufflevector(lo, hi, 0, 1, 2, 3, 4, 5, 6, 7);
        }

    float s_acc[2][4];
    #pragma unroll
    for (int g = 0; g < 2; ++g)
        #pragma unroll
        for (int r = 0; r < 4; ++r) s_acc[g][r] = 0.0f;

    // B base in LDS; phase f (0..15): addr = bp0 + (f>>2)*16384 + (f&3)*256
    //   (+8192 for kc=1, +1024 for hi 16 B of the 32-elem k-block)
    const char* bp0 = blds + kg * 2048 + rl * 16;

    i32x8 bfA0, bfA1, bfB0, bfB1;                // double-buffered B fragments
    f32x4 accA[2], accB[2];

    #define LOADB(D0, D1, F)                                                      \
        {                                                                         \
            const char* bq = bp0 + ((F) >> 2) * 16384 + ((F) & 3) * 256;          \
            i32x4 l0 = *reinterpret_cast<const i32x4*>(bq);                       \
            i32x4 l1 = *reinterpret_cast<const i32x4*>(bq + 1024);                \
            i32x4 l2 = *reinterpret_cast<const i32x4*>(bq + 8192);                \
            i32x4 l3 = *reinterpret_cast<const i32x4*>(bq + 9216);                \
            D0 = __builtin_shufflevector(l0, l1, 0, 1, 2, 3, 4, 5, 6, 7);         \
            D1 = __builtin_shufflevector(l2, l3, 0, 1, 2, 3, 4, 5, 6, 7);         \
        }

    #define MFMA4(ACC, B0, B1)                                                    \
        {                                                                         \
            _Pragma("unroll")                                                     \
            for (int g = 0; g < 2; ++g) ACC[g] = (f32x4){0.f, 0.f, 0.f, 0.f};     \
            _Pragma("unroll")                                                     \
            for (int g = 0; g < 2; ++g)                                           \
                asm("v_mfma_f32_16x16x128_f8f6f4 %0, %1, %2, %0"                  \
                    : "+v"(ACC[g]) : "v"(afrag[g][0]), "v"(B0));                  \
            _Pragma("unroll")                                                     \
            for (int g = 0; g < 2; ++g)                                           \
                asm("v_mfma_f32_16x16x128_f8f6f4 %0, %1, %2, %0"                  \
                    : "+v"(ACC[g]) : "v"(afrag[g][1]), "v"(B1));                  \
        }

    #define EXPSUM(ACC, F)                                                        \
        {                                                                         \
            float cthr = 0.0f;                                                    \
            _Pragma("unroll")                                                     \
            for (int g = 0; g < 2; ++g)                                           \
                _Pragma("unroll")                                                 \
                for (int r = 0; r < 4; ++r) {                                     \
                    float e = __builtin_amdgcn_exp2f(fmaf(ACC[g][r], EXPC, EXPB)); \
                    s_acc[g][r] += e;                                             \
                    cthr += e;                                                    \
                }                                                                 \
            cthr += __shfl_xor(cthr, 16, 64);                                     \
            cthr += __shfl_xor(cthr, 32, 64);                                     \
            if (offdiag && lane < 16)                                             \
                cs[wave][((F) >> 2) * 64 + ((F) & 3) * 16 + rl] = cthr;           \
        }

    __syncthreads();                       // B panel landed (drains vmcnt)

    // Software pipeline: loads one phase ahead; EXPSUM one phase behind.
    LOADB(bfA0, bfA1, 0);
    LOADB(bfB0, bfB1, 1);
    MFMA4(accA, bfA0, bfA1);               // phase 0
    #pragma unroll 1
    for (int fo = 0; fo < 7; ++fo) {
        const int f1 = 2 * fo + 1, f2 = 2 * fo + 2;
        LOADB(bfA0, bfA1, f2);             // issue f2 loads (bfA free: consumed)
        MFMA4(accB, bfB0, bfB1);           // phase f1 (loads a phase old)
        asm volatile("s_nop 7");
        EXPSUM(accA, f1 - 1);
        LOADB(bfB0, bfB1, f2 + 1);         // issue f2+1 loads (<=15)
        MFMA4(accA, bfA0, bfA1);           // phase f2
        asm volatile("s_nop 7");
        EXPSUM(accB, f2 - 1);
    }
    MFMA4(accB, bfB0, bfB1);               // phase 15
    asm volatile("s_nop 7");
    EXPSUM(accA, 14);
    asm volatile("s_nop 7");
    EXPSUM(accB, 15);

    // Row-sums over the 16 col-lanes (rl); rows i0 + g*16 + kg*4 + r -> slot chunk.
    #pragma unroll
    for (int g = 0; g < 2; ++g)
        #pragma unroll
        for (int r = 0; r < 4; ++r) {
            float v = s_acc[g][r];
            #pragma unroll
            for (int off = 1; off < 16; off <<= 1) v += __shfl_xor(v, off, 64);
            if (rl == 0)
                partial[chunk * N_SZ + i0 + g * 16 + kg * 4 + r] = v;
        }

    // Col-sums: combine 8 waves, write 256 cols of the chunk-tile -> slot rt.
    if (offdiag) {
        __syncthreads();
        if (t < 256) {
            float v = 0.0f;
            #pragma unroll
            for (int w = 0; w < 8; ++w) v += cs[w][t];
            partial[rt * N_SZ + chunk * 256 + t] = v;
        }
    }
    #undef LOADB
    #undef MFMA4
    #undef EXPSUM
}

// ---- Kernel 3: per-row lse - pos; device-scope atomic final reduce ----
__global__ __launch_bounds__(256) void rowsum_kernel(const float* __restrict__ partial,
                                                     const float* __restrict__ pos,
                                                     float* __restrict__ accf,
                                                     unsigned* __restrict__ counter,
                                                     float* __restrict__ out) {
    const int row = blockIdx.x * 256 + threadIdx.x;
    float s = -1.0f;                       // remove diagonal exp(~0)=1
    #pragma unroll
    for (int c = 0; c < 32; ++c) s += partial[c * N_SZ + row];
    float acc = 2.0f + logf(s) - pos[row];
    #pragma unroll
    for (int off = 32; off; off >>= 1) acc += __shfl_xor(acc, off, 64);
    __shared__ float w[4];
    if ((threadIdx.x & 63) == 0) w[threadIdx.x >> 6] = acc;
    __syncthreads();
    if (threadIdx.x == 0) {
        atomicAdd(accf, w[0] + w[1] + w[2] + w[3]);
        __threadfence();
        unsigned old = atomicAdd(counter, 1u);
        if (old == 31u) {
            float tot = atomicAdd(accf, 0.0f);     // atomic read of final sum
            out[0] = tot / (float)N_SZ;
        }
    }
}

extern "C" void kernel_launch(void* const* d_in, const int* in_sizes, int n_in,
                              void* d_out, int out_size, void* d_ws, size_t ws_size,
                              hipStream_t stream) {
    const float* zi = (const float*)d_in[0];
    const float* zj = (const float*)d_in[1];

    char* ws = (char*)d_ws;
    char* znb       = ws;                                   // 2 MB fp8 k-seg layout
    float* pos      = (float*)(ws + 2097152);               // 32 KB
    float* partial  = (float*)(ws + 2097152 + 32768);       // 32*8192*4 = 1 MB
    float* accf     = (float*)(ws + 2097152 + 32768 + 1048576);
    unsigned* counter = (unsigned*)(ws + 2097152 + 32768 + 1048576 + 4);
    float* out = (float*)d_out;

    prep_kernel<<<B_SZ / 4, 256, 0, stream>>>(zi, zj, znb, pos, accf, counter);
    simlse_kernel<<<528, 512, 0, stream>>>(znb, partial);
    rowsum_kernel<<<32, 256, 0, stream>>>(partial, pos, accf, counter, out);
}

// Round 18
// 31.733 us; speedup vs baseline: 2.7551x; 1.0176x over previous
//
#include <hip/hip_runtime.h>
#include <hip/hip_bf16.h>
#include <cmath>

#define B_SZ 4096
#define N_SZ 8192
#define D_SZ 256
#define EPS 1e-8f
// zn is stored as fp8 e4m3 scaled by 16 -> acc = 256*cos.
// exp(sim-2) with sim = 2*cos = acc/128:  exp2( acc*log2e/128 - 2*log2e )
#define EXPC 0.01127105500694503f      // log2(e)/128
#define EXPB -2.8853900817779268f      // -2*log2(e)

typedef __attribute__((ext_vector_type(4))) float f32x4;
typedef __attribute__((ext_vector_type(4))) int   i32x4;
typedef __attribute__((ext_vector_type(8))) int   i32x8;

__device__ __forceinline__ void dma16(const void* g, void* l) {
    __builtin_amdgcn_global_load_lds(
        (const __attribute__((address_space(1))) unsigned int*)g,
        (__attribute__((address_space(3))) unsigned int*)l, 16, 0, 0);
}

// fp8 k-segment-transposed panel layout (1 byte/elem):
//   byte(row,k) = (row>>6)*16384 + (k>>4)*1024 + (row&63)*16 + (k&15)
// subpanel = 64 rows x 256 k = 16 KB. One K=128 MFMA operand (32 fp8) = two
// 16-B loads 1024 B apart.

// ---- Kernel 1: norms + pos (fp32 exact) + fp8 ZN + zero the reduce ctrl. ----
__global__ __launch_bounds__(256) void prep_kernel(const float* __restrict__ zi,
                                                   const float* __restrict__ zj,
                                                   char* __restrict__ znb,
                                                   float* __restrict__ pos,
                                                   float* __restrict__ accf,
                                                   unsigned* __restrict__ counter) {
    if (blockIdx.x == 0 && threadIdx.x == 0) { *accf = 0.0f; *counter = 0u; }
    const int wave = threadIdx.x >> 6, lane = threadIdx.x & 63;
    const int i = blockIdx.x * 4 + wave;               // 0..B-1
    float4 a = reinterpret_cast<const float4*>(zi + (size_t)i * D_SZ)[lane];
    float4 b = reinterpret_cast<const float4*>(zj + (size_t)i * D_SZ)[lane];
    float ssa = a.x * a.x + a.y * a.y + a.z * a.z + a.w * a.w;
    float ssb = b.x * b.x + b.y * b.y + b.z * b.z + b.w * b.w;
    float dab = a.x * b.x + a.y * b.y + a.z * b.z + a.w * b.w;
    #pragma unroll
    for (int off = 32; off; off >>= 1) {
        ssa += __shfl_xor(ssa, off, 64);
        ssb += __shfl_xor(ssb, off, 64);
        dab += __shfl_xor(dab, off, 64);
    }
    const float invna = 1.0f / fmaxf(sqrtf(ssa), EPS);
    const float invnb = 1.0f / fmaxf(sqrtf(ssb), EPS);
    if (lane == 0) {
        float p = dab * invna * invnb * 2.0f;
        pos[i] = p;
        pos[i + B_SZ] = p;
    }
    // lane covers k = 4*lane .. 4*lane+3; seg = lane>>2, in-seg byte = (lane&3)*4.
    const float sa = invna * 16.0f, sb = invnb * 16.0f;
    const int koff = (lane >> 2) * 1024 + (lane & 3) * 4;
    {
        int pk = __builtin_amdgcn_cvt_pk_fp8_f32(a.x * sa, a.y * sa, 0, false);
        pk     = __builtin_amdgcn_cvt_pk_fp8_f32(a.z * sa, a.w * sa, pk, true);
        *reinterpret_cast<int*>(znb + (size_t)(i >> 6) * 16384 + koff + (i & 63) * 16) = pk;
    }
    {
        const int r = i + B_SZ;
        int pk = __builtin_amdgcn_cvt_pk_fp8_f32(b.x * sb, b.y * sb, 0, false);
        pk     = __builtin_amdgcn_cvt_pk_fp8_f32(b.z * sb, b.w * sb, pk, true);
        *reinterpret_cast<int*>(znb + (size_t)(r >> 6) * 16384 + koff + (r & 63) * 16) = pk;
    }
}

// ---- Kernel 2: SYMMETRIC fp8 K=128 sim-GEMM + exp-sum, M_w=64 / 1-generation ----
// 528 blocks x 256 thr (4 waves, M_w=64 rows each). launch_bounds(256,3):
// 3 blocks/CU -> 768 slots >= 528 -> SINGLE dispatch generation.
// B panel staged in two 32 KB halves (cols 0-127, 128-255); restage DMA hidden
// by the other resident blocks + deferred EXPSUM(7). Each B fragment feeds 8
// MFMAs (was 4) -> LDS read traffic halves. XCD-paired decode (r17).
__global__ __launch_bounds__(256, 3) void simlse_kernel(const char* __restrict__ znb,
                                                        float* __restrict__ partial) {
    __shared__ __attribute__((aligned(16))) char blds[32768];
    __shared__ float cs[4][256];

    const int t = threadIdx.x;
    const int wave = t >> 6, lane = t & 63;

    // XCD-paired decode: XCD x owns chunk-pairs (x, 31-x) and (x+8, 23-x).
    int rt, chunk;
    {
        const int x = blockIdx.x & 7;
        int j = blockIdx.x >> 3;                 // 0..65 within XCD
        int p = x;
        if (j >= 33) { j -= 33; p = x + 8; }
        if (j <= p) { rt = j; chunk = p; }
        else        { rt = j - (p + 1); chunk = 31 - p; }
    }
    const bool offdiag = (rt != chunk);

    const int rl = lane & 15;                    // A-row / B-col within fragment
    const int kg = lane >> 4;                    // 32-elem k-block index
    const int i0 = rt * 256 + wave * 64;         // wave's first row

    // Stage half H of chunk's panel (32 KB contiguous): 256 thr x 8 x 16 B.
    #define STAGE(H)                                                              \
        {                                                                         \
            const char* gp = znb + (size_t)chunk * 65536 + (H) * 32768 + t * 16;  \
            char* lp = blds + t * 16;                                             \
            _Pragma("unroll")                                                     \
            for (int c = 0; c < 8; ++c) dma16(gp + c * 4096, lp + c * 4096);      \
        }

    STAGE(0);                                    // issue half-0 DMA first

    // A panel: wave owns subpanel rt*4+wave (64 rows). 4 rowgroups x 2 k-chunks.
    const char* ap = znb + (size_t)(rt * 4 + wave) * 16384 + rl * 16;
    i32x8 afrag[4][2];
    #pragma unroll
    for (int g = 0; g < 4; ++g)
        #pragma unroll
        for (int kc = 0; kc < 2; ++kc) {
            i32x4 lo = *reinterpret_cast<const i32x4*>(
                ap + (kc * 8 + kg * 2) * 1024 + g * 256);
            i32x4 hi = *reinterpret_cast<const i32x4*>(
                ap + (kc * 8 + kg * 2 + 1) * 1024 + g * 256);
            afrag[g][kc] = __builtin_shufflevector(lo, hi, 0, 1, 2, 3, 4, 5, 6, 7);
        }

    float s_acc[4][4];
    #pragma unroll
    for (int g = 0; g < 4; ++g)
        #pragma unroll
        for (int r = 0; r < 4; ++r) s_acc[g][r] = 0.0f;

    // B base in LDS; local phase fl (0..7): addr = bp0 + (fl>>2)*16384 + (fl&3)*256
    //   (+8192 for kc=1, +1024 for hi 16 B of the 32-elem k-block)
    const char* bp0 = blds + kg * 2048 + rl * 16;

    i32x8 bf0, bf1;
    f32x4 accA[4], accB[4];

    #define LOADB(FL)                                                             \
        {                                                                         \
            const char* bq = bp0 + ((FL) >> 2) * 16384 + ((FL) & 3) * 256;        \
            i32x4 l0 = *reinterpret_cast<const i32x4*>(bq);                       \
            i32x4 l1 = *reinterpret_cast<const i32x4*>(bq + 1024);                \
            i32x4 l2 = *reinterpret_cast<const i32x4*>(bq + 8192);                \
            i32x4 l3 = *reinterpret_cast<const i32x4*>(bq + 9216);                \
            bf0 = __builtin_shufflevector(l0, l1, 0, 1, 2, 3, 4, 5, 6, 7);        \
            bf1 = __builtin_shufflevector(l2, l3, 0, 1, 2, 3, 4, 5, 6, 7);        \
        }

    #define MFMA8(ACC)                                                            \
        {                                                                         \
            _Pragma("unroll")                                                     \
            for (int g = 0; g < 4; ++g) ACC[g] = (f32x4){0.f, 0.f, 0.f, 0.f};     \
            _Pragma("unroll")                                                     \
            for (int g = 0; g < 4; ++g)                                           \
                asm("v_mfma_f32_16x16x128_f8f6f4 %0, %1, %2, %0"                  \
                    : "+v"(ACC[g]) : "v"(afrag[g][0]), "v"(bf0));                 \
            _Pragma("unroll")                                                     \
            for (int g = 0; g < 4; ++g)                                           \
                asm("v_mfma_f32_16x16x128_f8f6f4 %0, %1, %2, %0"                  \
                    : "+v"(ACC[g]) : "v"(afrag[g][1]), "v"(bf1));                 \
        }

    #define EXPSUM(ACC, F)                                                        \
        {                                                                         \
            float cthr = 0.0f;                                                    \
            _Pragma("unroll")                                                     \
            for (int g = 0; g < 4; ++g)                                           \
                _Pragma("unroll")                                                 \
                for (int r = 0; r < 4; ++r) {                                     \
                    float e = __builtin_amdgcn_exp2f(fmaf(ACC[g][r], EXPC, EXPB)); \
                    s_acc[g][r] += e;                                             \
                    cthr += e;                                                    \
                }                                                                 \
            cthr += __shfl_xor(cthr, 16, 64);                                     \
            cthr += __shfl_xor(cthr, 32, 64);                                     \
            if (offdiag && lane < 16)                                             \
                cs[wave][(F) * 16 + rl] = cthr;                                   \
        }

    __syncthreads();                       // half-0 landed (drains vmcnt)

    // ---- half 0: global phases 0..7, acc ping-pong ----
    LOADB(0); MFMA8(accA);
    #pragma unroll 1
    for (int fo = 0; fo < 3; ++fo) {
        const int f1 = 2 * fo + 1, f2 = 2 * fo + 2;
        LOADB(f1); MFMA8(accB);
        asm volatile("s_nop 7");
        EXPSUM(accA, f1 - 1);
        LOADB(f2); MFMA8(accA);
        asm volatile("s_nop 7");
        EXPSUM(accB, f2 - 1);
    }
    LOADB(7); MFMA8(accB);
    asm volatile("s_nop 7");
    EXPSUM(accA, 6);

    __syncthreads();                       // all waves done reading half 0
    STAGE(1);                              // issue half-1 DMA
    EXPSUM(accB, 7);                       // deferred exp hides under the DMA
    __syncthreads();                       // half-1 landed (drains vmcnt)

    // ---- half 1: global phases 8..15 ----
    LOADB(0); MFMA8(accA);
    #pragma unroll 1
    for (int fo = 0; fo < 3; ++fo) {
        const int f1 = 2 * fo + 1, f2 = 2 * fo + 2;
        LOADB(f1); MFMA8(accB);
        asm volatile("s_nop 7");
        EXPSUM(accA, 8 + f1 - 1);
        LOADB(f2); MFMA8(accA);
        asm volatile("s_nop 7");
        EXPSUM(accB, 8 + f2 - 1);
    }
    LOADB(7); MFMA8(accB);
    asm volatile("s_nop 7");
    EXPSUM(accA, 14);
    asm volatile("s_nop 7");
    EXPSUM(accB, 15);

    // Row-sums over the 16 col-lanes (rl); rows i0 + g*16 + kg*4 + r -> slot chunk.
    #pragma unroll
    for (int g = 0; g < 4; ++g)
        #pragma unroll
        for (int r = 0; r < 4; ++r) {
            float v = s_acc[g][r];
            #pragma unroll
            for (int off = 1; off < 16; off <<= 1) v += __shfl_xor(v, off, 64);
            if (rl == 0)
                partial[chunk * N_SZ + i0 + g * 16 + kg * 4 + r] = v;
        }

    // Col-sums: combine 4 waves, write 256 cols of the chunk-tile -> slot rt.
    if (offdiag) {
        __syncthreads();
        float v = cs[0][t] + cs[1][t] + cs[2][t] + cs[3][t];
        partial[rt * N_SZ + chunk * 256 + t] = v;
    }
    #undef STAGE
    #undef LOADB
    #undef MFMA8
    #undef EXPSUM
}

// ---- Kernel 3: per-row lse - pos; device-scope atomic final reduce ----
__global__ __launch_bounds__(256) void rowsum_kernel(const float* __restrict__ partial,
                                                     const float* __restrict__ pos,
                                                     float* __restrict__ accf,
                                                     unsigned* __restrict__ counter,
                                                     float* __restrict__ out) {
    const int row = blockIdx.x * 256 + threadIdx.x;
    float s = -1.0f;                       // remove diagonal exp(~0)=1
    #pragma unroll
    for (int c = 0; c < 32; ++c) s += partial[c * N_SZ + row];
    float acc = 2.0f + logf(s) - pos[row];
    #pragma unroll
    for (int off = 32; off; off >>= 1) acc += __shfl_xor(acc, off, 64);
    __shared__ float w[4];
    if ((threadIdx.x & 63) == 0) w[threadIdx.x >> 6] = acc;
    __syncthreads();
    if (threadIdx.x == 0) {
        atomicAdd(accf, w[0] + w[1] + w[2] + w[3]);
        __threadfence();
        unsigned old = atomicAdd(counter, 1u);
        if (old == 31u) {
            float tot = atomicAdd(accf, 0.0f);     // atomic read of final sum
            out[0] = tot / (float)N_SZ;
        }
    }
}

extern "C" void kernel_launch(void* const* d_in, const int* in_sizes, int n_in,
                              void* d_out, int out_size, void* d_ws, size_t ws_size,
                              hipStream_t stream) {
    const float* zi = (const float*)d_in[0];
    const float* zj = (const float*)d_in[1];

    char* ws = (char*)d_ws;
    char* znb       = ws;                                   // 2 MB fp8 k-seg layout
    float* pos      = (float*)(ws + 2097152);               // 32 KB
    float* partial  = (float*)(ws + 2097152 + 32768);       // 32*8192*4 = 1 MB
    float* accf     = (float*)(ws + 2097152 + 32768 + 1048576);
    unsigned* counter = (unsigned*)(ws + 2097152 + 32768 + 1048576 + 4);
    float* out = (float*)d_out;

    prep_kernel<<<B_SZ / 4, 256, 0, stream>>>(zi, zj, znb, pos, accf, counter);
    simlse_kernel<<<528, 256, 0, stream>>>(znb, partial);
    rowsum_kernel<<<32, 256, 0, stream>>>(partial, pos, accf, counter, out);
}